// Round 3
// baseline (467.025 us; speedup 1.0000x reference)
//
#include <hip/hip_runtime.h>

#define EMBED 768
#define NH 12
#define HD 64
#define MEMN 64
#define BB 8
#define TT 1024
#define ROWS (BB*TT)          // 8192
#define QKV_N 2304
#define QSZ 6291456           // B*NH*TT*HD (elements)

typedef short bf16x8_t __attribute__((ext_vector_type(8)));
typedef float f32x4_t __attribute__((ext_vector_type(4)));

__device__ __forceinline__ unsigned short f2b(float f){
    union { float f; unsigned int i; } v; v.f = f;
    unsigned int x = v.i;
    unsigned int r = x + 0x7fffu + ((x >> 16) & 1u);
    return (unsigned short)(r >> 16);
}

// ---- 64x64-tile MFMA GEMM: A fp32 or bf16 (row-major MxK), B fp32 (row-major KxN) ----
// staging converts fp32 -> bf16 (RNE); fp32 accumulate; bias fp32.
// mode 0: QKV (M=8192,N=2304): q -> dq_u16 [B,T,768] bf16; k,v -> dkv bf16 [s][B,H,T,D]
// mode 1: out proj: dq_f32[row*N + c] fp32
// mode 2: mem proj (M=64,N=768): dq_u16[(h*64+row)*64 + d] bf16
__global__ __launch_bounds__(256) void gemm_bias(
    const void* __restrict__ A, int a_is_bf16,
    const float* __restrict__ B,
    const float* __restrict__ bias,
    unsigned short* __restrict__ dq_u16,
    float* __restrict__ dq_f32,
    unsigned short* __restrict__ dkv,
    int M, int N, int K, int mode)
{
    __shared__ unsigned short As[64][40];
    __shared__ unsigned short Bs[64][40];   // transposed: Bs[n][k]
    int t = threadIdx.x;
    int wave = t >> 6, lane = t & 63;
    int ln = lane & 15, lq = lane >> 4;
    int bm = blockIdx.y * 64, bn = blockIdx.x * 64;

    f32x4_t acc[4];
    for (int i = 0; i < 4; i++) acc[i] = (f32x4_t)(0.f);

    int sm = t >> 2;            // A stage: row 0..63
    int sk = (t & 3) * 8;       // A stage: k offset (0,8,16,24)
    int bk = t >> 3;            // B stage: k 0..31
    int bn8 = (t & 7) * 8;      // B stage: n offset

    for (int k0 = 0; k0 < K; k0 += 32) {
        __syncthreads();
        if (a_is_bf16) {
            const unsigned short* Au = (const unsigned short*)A;
            *(bf16x8_t*)&As[sm][sk] = *(const bf16x8_t*)&Au[(size_t)(bm + sm) * K + k0 + sk];
        } else {
            const float* Af = (const float*)A;
            float4 f0 = *(const float4*)&Af[(size_t)(bm + sm) * K + k0 + sk];
            float4 f1 = *(const float4*)&Af[(size_t)(bm + sm) * K + k0 + sk + 4];
            unsigned short* ap = &As[sm][sk];
            ap[0] = f2b(f0.x); ap[1] = f2b(f0.y); ap[2] = f2b(f0.z); ap[3] = f2b(f0.w);
            ap[4] = f2b(f1.x); ap[5] = f2b(f1.y); ap[6] = f2b(f1.z); ap[7] = f2b(f1.w);
        }
        {
            float4 g0 = *(const float4*)&B[(size_t)(k0 + bk) * N + bn + bn8];
            float4 g1 = *(const float4*)&B[(size_t)(k0 + bk) * N + bn + bn8 + 4];
            Bs[bn8 + 0][bk] = f2b(g0.x); Bs[bn8 + 1][bk] = f2b(g0.y);
            Bs[bn8 + 2][bk] = f2b(g0.z); Bs[bn8 + 3][bk] = f2b(g0.w);
            Bs[bn8 + 4][bk] = f2b(g1.x); Bs[bn8 + 5][bk] = f2b(g1.y);
            Bs[bn8 + 6][bk] = f2b(g1.z); Bs[bn8 + 7][bk] = f2b(g1.w);
        }
        __syncthreads();
        bf16x8_t a = *(bf16x8_t*)&As[wave * 16 + ln][lq * 8];
        for (int nt = 0; nt < 4; nt++) {
            bf16x8_t bf = *(bf16x8_t*)&Bs[nt * 16 + ln][lq * 8];
            acc[nt] = __builtin_amdgcn_mfma_f32_16x16x32_bf16(a, bf, acc[nt], 0, 0, 0);
        }
    }

    for (int nt = 0; nt < 4; nt++) {
        int c = bn + nt * 16 + ln;
        float bv = bias[c];
        for (int r = 0; r < 4; r++) {
            int row = bm + wave * 16 + lq * 4 + r;
            float val = acc[nt][r] + bv;
            if (mode == 0) {
                int bb = row >> 10, tt = row & 1023;
                int s = c / 768; int rem = c - s * 768;
                if (s == 0) {
                    dq_u16[(size_t)row * 768 + rem] = f2b(val);          // q as [B,T,C] bf16
                } else {
                    int h = rem >> 6, d = rem & 63;
                    dkv[(size_t)(s - 1) * QSZ +
                        (((size_t)(bb * 12 + h) * 1024 + tt) << 6) + d] = f2b(val);
                }
            } else if (mode == 1) {
                dq_f32[(size_t)row * N + c] = val;                       // final fp32
            } else {
                int h = c >> 6, d = c & 63;
                dq_u16[((h * 64 + row) << 6) + d] = f2b(val);            // mem [H,M,D] bf16
            }
        }
    }
}

// ---- flash attention (local T=1024, online softmax) + memory attention; all bf16 I/O ----
__global__ __launch_bounds__(256) void attn_kernel(
    const unsigned short* __restrict__ qin,     // [B,T,768] bf16
    const unsigned short* __restrict__ k_ws,    // [B,H,T,D] bf16
    const unsigned short* __restrict__ v_ws,    // [B,H,T,D] bf16
    const unsigned short* __restrict__ mem_ws,  // [H,M,D]   bf16
    unsigned short* __restrict__ aout)          // [B,T,768] bf16
{
    __shared__ unsigned short Qs[64][72];
    __shared__ unsigned short Ks[64][72];
    __shared__ unsigned short Vs[64][72];   // transposed: Vs[d][key]
    __shared__ unsigned short Ps[64][72];

    int t = threadIdx.x;
    int wave = t >> 6, lane = t & 63;
    int ln = lane & 15, lq = lane >> 4;
    int qt = blockIdx.x, h = blockIdx.y, b = blockIdx.z;

    const size_t bh = (size_t)b * NH + h;
    const unsigned short* qp = qin + ((size_t)(b * TT + qt * 64)) * 768 + h * 64;
    unsigned short* op = aout + ((size_t)(b * TT + qt * 64)) * 768 + h * 64;
    const unsigned short* kp = k_ws + bh * TT * 64;
    const unsigned short* vp = v_ws + bh * TT * 64;
    const unsigned short* mp = mem_ws + (size_t)h * MEMN * 64;

    for (int i = 0; i < 2; i++) {
        int idx = i * 256 + t;
        int r = idx >> 3, c8 = (idx & 7) * 8;
        *(bf16x8_t*)&Qs[r][c8] = *(const bf16x8_t*)&qp[(size_t)r * 768 + c8];
    }

    const float CS = 0.125f * 1.44269504088896340736f;  // 1/sqrt(64) * log2(e)

    float m_i[4], l_i[4];
    f32x4_t accO[4];
    for (int r = 0; r < 4; r++) { m_i[r] = -1e30f; l_i[r] = 0.f; }
    for (int nt = 0; nt < 4; nt++) accO[nt] = (f32x4_t)(0.f);

    for (int kt = 0; kt < 16; kt++) {
        __syncthreads();
        for (int i = 0; i < 2; i++) {
            int idx = i * 256 + t;
            int r = idx >> 3, c8 = (idx & 7) * 8;
            *(bf16x8_t*)&Ks[r][c8] = *(const bf16x8_t*)&kp[((size_t)kt * 64 + r) * 64 + c8];
            bf16x8_t v = *(const bf16x8_t*)&vp[((size_t)kt * 64 + r) * 64 + c8];
            for (int j = 0; j < 8; j++) Vs[c8 + j][r] = ((unsigned short*)&v)[j];
        }
        __syncthreads();

        f32x4_t s[4];
        for (int nt = 0; nt < 4; nt++) s[nt] = (f32x4_t)(0.f);
        for (int kk = 0; kk < 2; kk++) {
            bf16x8_t a = *(bf16x8_t*)&Qs[wave * 16 + ln][kk * 32 + lq * 8];
            for (int nt = 0; nt < 4; nt++) {
                bf16x8_t bf = *(bf16x8_t*)&Ks[nt * 16 + ln][kk * 32 + lq * 8];
                s[nt] = __builtin_amdgcn_mfma_f32_16x16x32_bf16(a, bf, s[nt], 0, 0, 0);
            }
        }
        for (int nt = 0; nt < 4; nt++)
            for (int r = 0; r < 4; r++) s[nt][r] *= CS;

        float alpha[4];
        for (int r = 0; r < 4; r++) {
            float mx = fmaxf(fmaxf(s[0][r], s[1][r]), fmaxf(s[2][r], s[3][r]));
            mx = fmaxf(mx, __shfl_xor(mx, 1));
            mx = fmaxf(mx, __shfl_xor(mx, 2));
            mx = fmaxf(mx, __shfl_xor(mx, 4));
            mx = fmaxf(mx, __shfl_xor(mx, 8));
            float mnew = fmaxf(m_i[r], mx);
            alpha[r] = exp2f(m_i[r] - mnew);
            float rs = 0.f;
            for (int nt = 0; nt < 4; nt++) {
                float p = exp2f(s[nt][r] - mnew);
                s[nt][r] = p;
                rs += p;
            }
            rs += __shfl_xor(rs, 1);
            rs += __shfl_xor(rs, 2);
            rs += __shfl_xor(rs, 4);
            rs += __shfl_xor(rs, 8);
            l_i[r] = l_i[r] * alpha[r] + rs;
            m_i[r] = mnew;
        }
        for (int nt = 0; nt < 4; nt++) {
            for (int r = 0; r < 4; r++) {
                Ps[wave * 16 + lq * 4 + r][nt * 16 + ln] = f2b(s[nt][r]);
                accO[nt][r] *= alpha[r];
            }
        }
        __syncthreads();
        for (int kk = 0; kk < 2; kk++) {
            bf16x8_t a = *(bf16x8_t*)&Ps[wave * 16 + ln][kk * 32 + lq * 8];
            for (int nt = 0; nt < 4; nt++) {
                bf16x8_t bf = *(bf16x8_t*)&Vs[nt * 16 + ln][kk * 32 + lq * 8];
                accO[nt] = __builtin_amdgcn_mfma_f32_16x16x32_bf16(a, bf, accO[nt], 0, 0, 0);
            }
        }
    }

    // memory attention: independent softmax over 64 projected-memory keys
    __syncthreads();
    for (int i = 0; i < 2; i++) {
        int idx = i * 256 + t;
        int r = idx >> 3, c8 = (idx & 7) * 8;
        bf16x8_t v = *(const bf16x8_t*)&mp[r * 64 + c8];
        *(bf16x8_t*)&Ks[r][c8] = v;
        for (int j = 0; j < 8; j++) Vs[c8 + j][r] = ((unsigned short*)&v)[j];
    }
    __syncthreads();

    f32x4_t s2[4];
    for (int nt = 0; nt < 4; nt++) s2[nt] = (f32x4_t)(0.f);
    for (int kk = 0; kk < 2; kk++) {
        bf16x8_t a = *(bf16x8_t*)&Qs[wave * 16 + ln][kk * 32 + lq * 8];
        for (int nt = 0; nt < 4; nt++) {
            bf16x8_t bf = *(bf16x8_t*)&Ks[nt * 16 + ln][kk * 32 + lq * 8];
            s2[nt] = __builtin_amdgcn_mfma_f32_16x16x32_bf16(a, bf, s2[nt], 0, 0, 0);
        }
    }
    float l2[4];
    for (int r = 0; r < 4; r++) {
        for (int nt = 0; nt < 4; nt++) s2[nt][r] *= CS;
        float mx = fmaxf(fmaxf(s2[0][r], s2[1][r]), fmaxf(s2[2][r], s2[3][r]));
        mx = fmaxf(mx, __shfl_xor(mx, 1));
        mx = fmaxf(mx, __shfl_xor(mx, 2));
        mx = fmaxf(mx, __shfl_xor(mx, 4));
        mx = fmaxf(mx, __shfl_xor(mx, 8));
        float rs = 0.f;
        for (int nt = 0; nt < 4; nt++) {
            float p = exp2f(s2[nt][r] - mx);
            s2[nt][r] = p;
            rs += p;
        }
        rs += __shfl_xor(rs, 1);
        rs += __shfl_xor(rs, 2);
        rs += __shfl_xor(rs, 4);
        rs += __shfl_xor(rs, 8);
        l2[r] = rs;
    }
    for (int nt = 0; nt < 4; nt++)
        for (int r = 0; r < 4; r++)
            Ps[wave * 16 + lq * 4 + r][nt * 16 + ln] = f2b(s2[nt][r]);
    __syncthreads();

    f32x4_t accM[4];
    for (int nt = 0; nt < 4; nt++) accM[nt] = (f32x4_t)(0.f);
    for (int kk = 0; kk < 2; kk++) {
        bf16x8_t a = *(bf16x8_t*)&Ps[wave * 16 + ln][kk * 32 + lq * 8];
        for (int nt = 0; nt < 4; nt++) {
            bf16x8_t bf = *(bf16x8_t*)&Vs[nt * 16 + ln][kk * 32 + lq * 8];
            accM[nt] = __builtin_amdgcn_mfma_f32_16x16x32_bf16(a, bf, accM[nt], 0, 0, 0);
        }
    }

    for (int nt = 0; nt < 4; nt++) {
        for (int r = 0; r < 4; r++) {
            int lrow = wave * 16 + lq * 4 + r;
            int lcol = nt * 16 + ln;
            float val = accO[nt][r] / l_i[r] + accM[nt][r] / l2[r];
            op[(size_t)lrow * 768 + lcol] = f2b(val);
        }
    }
}

// ---------------- host ----------------
extern "C" void kernel_launch(void* const* d_in, const int* in_sizes, int n_in,
                              void* d_out, int out_size, void* d_ws, size_t ws_size,
                              hipStream_t stream) {
    const float* x      = (const float*)d_in[0];  // 8x1024x768
    const float* w_qkv  = (const float*)d_in[1];  // 768x2304
    const float* b_qkv  = (const float*)d_in[2];  // 2304
    const float* w_out  = (const float*)d_in[3];  // 768x768
    const float* b_out  = (const float*)d_in[4];  // 768
    const float* w_mem  = (const float*)d_in[5];  // 768x768
    const float* b_mem  = (const float*)d_in[6];  // 768
    const float* memory = (const float*)d_in[7];  // 1x64x768

    unsigned short* ws = (unsigned short*)d_ws;
    unsigned short* k_ws    = ws;                    // [B,H,T,D] bf16
    unsigned short* v_ws    = ws + (size_t)QSZ;      // [B,H,T,D] bf16
    unsigned short* attn_ws = ws + 2 * (size_t)QSZ;  // [B,T,C]   bf16
    unsigned short* mem_ws  = ws + 3 * (size_t)QSZ;  // [H,M,D]   bf16
    // q (bf16) parks in the first half of d_out; dead before final GEMM overwrites it.
    unsigned short* q_ws    = (unsigned short*)d_out;

    // 1) memory projection: (64x768) @ w_mem + b_mem -> mem_ws [H,M,D] bf16
    gemm_bias<<<dim3(EMBED / 64, 1), 256, 0, stream>>>(
        memory, 0, w_mem, b_mem, mem_ws, nullptr, nullptr, 64, EMBED, EMBED, 2);

    // 2) QKV projection: q -> q_ws [B,T,C] bf16; k,v -> ws [B,H,T,D] bf16
    gemm_bias<<<dim3(QKV_N / 64, ROWS / 64), 256, 0, stream>>>(
        x, 0, w_qkv, b_qkv, q_ws, nullptr, k_ws, ROWS, QKV_N, EMBED, 0);

    // 3) attention (local flash + memory) -> attn_ws [B,T,C] bf16
    attn_kernel<<<dim3(TT / 64, NH, BB), 256, 0, stream>>>(
        q_ws, k_ws, v_ws, mem_ws, attn_ws);

    // 4) output projection: attn_ws(bf16) @ w_out + b_out -> d_out fp32
    gemm_bias<<<dim3(EMBED / 64, ROWS / 64), 256, 0, stream>>>(
        attn_ws, 1, w_out, b_out, nullptr, (float*)d_out, nullptr, ROWS, EMBED, EMBED, 1);
}

// Round 4
// 359.968 us; speedup vs baseline: 1.2974x; 1.2974x over previous
//
#include <hip/hip_runtime.h>

#define EMBED 768
#define NH 12
#define HD 64
#define MEMN 64
#define BB 8
#define TT 1024
#define ROWS 8192
#define QKV_N 2304
#define QSZ 6291456           // B*T*C = B*NH*TT*HD (elements)

typedef short bf16x8_t __attribute__((ext_vector_type(8)));
typedef float f32x4_t __attribute__((ext_vector_type(4)));

__device__ __forceinline__ unsigned short f2b(float f){
    union { float f; unsigned int i; } v; v.f = f;
    unsigned int x = v.i;
    unsigned int r = x + 0x7fffu + ((x >> 16) & 1u);
    return (unsigned short)(r >> 16);
}

// async global->LDS, 16B per lane; lds base must be wave-uniform (lane*16 implicit)
__device__ __forceinline__ void gl16(const unsigned short* g, unsigned short* l){
    __builtin_amdgcn_global_load_lds(
        (const __attribute__((address_space(1))) void*)g,
        (__attribute__((address_space(3))) void*)l,
        16, 0, 0);
}

// ---------------- flat fp32 -> bf16 convert (8 elems/thread) ----------------
__global__ __launch_bounds__(256) void cvt_kernel(
    const float* __restrict__ in, unsigned short* __restrict__ out, int n)
{
    int i = (blockIdx.x * 256 + threadIdx.x) * 8;
    if (i >= n) return;
    float4 f0 = *(const float4*)&in[i];
    float4 f1 = *(const float4*)&in[i + 4];
    union { bf16x8_t v; unsigned short s[8]; } u;
    u.s[0] = f2b(f0.x); u.s[1] = f2b(f0.y); u.s[2] = f2b(f0.z); u.s[3] = f2b(f0.w);
    u.s[4] = f2b(f1.x); u.s[5] = f2b(f1.y); u.s[6] = f2b(f1.z); u.s[7] = f2b(f1.w);
    *(bf16x8_t*)&out[i] = u.v;
}

// ------------- fp32 [R][C] -> bf16 transposed [C][R] -------------
__global__ __launch_bounds__(256) void tcvt_kernel(
    const float* __restrict__ in, unsigned short* __restrict__ out, int R, int C)
{
    __shared__ unsigned short tile[32][33];
    int bc = blockIdx.x * 32, br = blockIdx.y * 32;
    int t = threadIdx.x;
    int lr = t >> 5, lc = t & 31;
    for (int i = 0; i < 4; i++) {
        int r = lr + i * 8;
        tile[r][lc] = f2b(in[(size_t)(br + r) * C + bc + lc]);
    }
    __syncthreads();
    for (int i = 0; i < 4; i++) {
        int r = lr + i * 8;
        out[(size_t)(bc + r) * R + br + lc] = tile[lc][r];
    }
}

// ---- m97-style 128x128 bf16 GEMM: A (MxK bf16), BT (NxK bf16), bias fp32 ----
// mode 0: QKV scatter  q -> dq [B,T,768] bf16; k,v -> dkv [s][B,H,T,D] bf16
// mode 1: fp32 row-major -> df
__global__ __launch_bounds__(256) void gemm_bt(
    const unsigned short* __restrict__ A,
    const unsigned short* __restrict__ BT,
    const float* __restrict__ bias,
    unsigned short* __restrict__ dq,
    unsigned short* __restrict__ dkv,
    float* __restrict__ df,
    int M, int N, int K, int mode)
{
    __shared__ unsigned short As[4096];   // 128 x 32, no pad (global_load_lds layout)
    __shared__ unsigned short Bs[4096];
    const int t = threadIdx.x;
    const int wave = t >> 6, lane = t & 63;
    const int ln = lane & 15, lq = lane >> 4;
    const int wm = (wave >> 1) * 64, wn = (wave & 1) * 64;
    const int bm = blockIdx.y * 128, bn = blockIdx.x * 128;

    f32x4_t acc[4][4];
    for (int i = 0; i < 4; i++)
        for (int j = 0; j < 4; j++) acc[i][j] = (f32x4_t)(0.f);

    // staging: wave w, lane l covers LDS bytes [issue*4096 + w*1024 + l*16)
    // = row (issue*64 + w*16 + l/4), cols (l%4)*8 .. +8 of the 128x32 tile
    const int srow = wave * 16 + (lane >> 2);
    const int scol = (lane & 3) * 8;
    unsigned short* a0 = &As[wave * 512];
    unsigned short* a1 = &As[2048 + wave * 512];
    unsigned short* b0 = &Bs[wave * 512];
    unsigned short* b1 = &Bs[2048 + wave * 512];
    const unsigned short* Ap = A + (size_t)(bm + srow) * K + scol;
    const unsigned short* Bp = BT + (size_t)(bn + srow) * K + scol;

    for (int k0 = 0; k0 < K; k0 += 32) {
        __syncthreads();
        gl16(Ap + k0, a0);
        gl16(Ap + (size_t)64 * K + k0, a1);
        gl16(Bp + k0, b0);
        gl16(Bp + (size_t)64 * K + k0, b1);
        __syncthreads();   // drains vmcnt(0) before barrier -> tiles visible

        bf16x8_t af[4], bfr[4];
        for (int mt = 0; mt < 4; mt++)
            af[mt] = *(bf16x8_t*)&As[(wm + mt * 16 + ln) * 32 + lq * 8];
        for (int nt = 0; nt < 4; nt++)
            bfr[nt] = *(bf16x8_t*)&Bs[(wn + nt * 16 + ln) * 32 + lq * 8];
        for (int mt = 0; mt < 4; mt++)
            for (int nt = 0; nt < 4; nt++)
                acc[mt][nt] = __builtin_amdgcn_mfma_f32_16x16x32_bf16(
                    af[mt], bfr[nt], acc[mt][nt], 0, 0, 0);
    }

    for (int nt = 0; nt < 4; nt++) {
        int c = bn + wn + nt * 16 + ln;
        float bv = bias[c];
        for (int mt = 0; mt < 4; mt++) {
            for (int r = 0; r < 4; r++) {
                int row = bm + wm + mt * 16 + lq * 4 + r;
                float val = acc[mt][nt][r] + bv;
                if (mode == 0) {
                    int bb = row >> 10, tt = row & 1023;
                    int s = c / 768; int rem = c - s * 768;
                    if (s == 0) {
                        dq[(size_t)row * 768 + rem] = f2b(val);
                    } else {
                        int h = rem >> 6, d = rem & 63;
                        dkv[(size_t)(s - 1) * QSZ +
                            (((size_t)(bb * 12 + h) * 1024 + tt) << 6) + d] = f2b(val);
                    }
                } else {
                    df[(size_t)row * N + c] = val;
                }
            }
        }
    }
}

// ---- memory projection (tiny): fp32 A (64x768), fp32 B (768x768) -> bf16 [H,M,D] ----
__global__ __launch_bounds__(256) void memproj_kernel(
    const float* __restrict__ A,
    const float* __restrict__ B,
    const float* __restrict__ bias,
    unsigned short* __restrict__ dmem)
{
    __shared__ unsigned short As[64][40];
    __shared__ unsigned short Bs[64][40];   // transposed: Bs[n][k]
    int t = threadIdx.x;
    int wave = t >> 6, lane = t & 63;
    int ln = lane & 15, lq = lane >> 4;
    int bn = blockIdx.x * 64;
    const int K = EMBED, N = EMBED;

    f32x4_t acc[4];
    for (int i = 0; i < 4; i++) acc[i] = (f32x4_t)(0.f);

    int sm = t >> 2, sk = (t & 3) * 8;
    int bk = t >> 3, bn8 = (t & 7) * 8;

    for (int k0 = 0; k0 < K; k0 += 32) {
        __syncthreads();
        {
            float4 f0 = *(const float4*)&A[(size_t)sm * K + k0 + sk];
            float4 f1 = *(const float4*)&A[(size_t)sm * K + k0 + sk + 4];
            unsigned short* ap = &As[sm][sk];
            ap[0] = f2b(f0.x); ap[1] = f2b(f0.y); ap[2] = f2b(f0.z); ap[3] = f2b(f0.w);
            ap[4] = f2b(f1.x); ap[5] = f2b(f1.y); ap[6] = f2b(f1.z); ap[7] = f2b(f1.w);
        }
        {
            float4 g0 = *(const float4*)&B[(size_t)(k0 + bk) * N + bn + bn8];
            float4 g1 = *(const float4*)&B[(size_t)(k0 + bk) * N + bn + bn8 + 4];
            Bs[bn8 + 0][bk] = f2b(g0.x); Bs[bn8 + 1][bk] = f2b(g0.y);
            Bs[bn8 + 2][bk] = f2b(g0.z); Bs[bn8 + 3][bk] = f2b(g0.w);
            Bs[bn8 + 4][bk] = f2b(g1.x); Bs[bn8 + 5][bk] = f2b(g1.y);
            Bs[bn8 + 6][bk] = f2b(g1.z); Bs[bn8 + 7][bk] = f2b(g1.w);
        }
        __syncthreads();
        bf16x8_t a = *(bf16x8_t*)&As[wave * 16 + ln][lq * 8];
        for (int nt = 0; nt < 4; nt++) {
            bf16x8_t bf = *(bf16x8_t*)&Bs[nt * 16 + ln][lq * 8];
            acc[nt] = __builtin_amdgcn_mfma_f32_16x16x32_bf16(a, bf, acc[nt], 0, 0, 0);
        }
    }

    for (int nt = 0; nt < 4; nt++) {
        int c = bn + nt * 16 + ln;
        float bv = bias[c];
        for (int r = 0; r < 4; r++) {
            int row = wave * 16 + lq * 4 + r;   // 0..63
            int h = c >> 6, d = c & 63;
            dmem[((h * 64 + row) << 6) + d] = f2b(acc[nt][r] + bv);
        }
    }
}

// ---- flash attention (local T=1024, online softmax) + memory attention; in-place over q ----
__global__ __launch_bounds__(256) void attn_kernel(
    unsigned short* __restrict__ qio,           // [B,T,768] bf16, in/out
    const unsigned short* __restrict__ k_ws,    // [B,H,T,D] bf16
    const unsigned short* __restrict__ v_ws,    // [B,H,T,D] bf16
    const unsigned short* __restrict__ mem_ws)  // [H,M,D]   bf16
{
    __shared__ unsigned short Qs[64][72];
    __shared__ unsigned short Ks[64][72];
    __shared__ unsigned short Vs[64][72];   // transposed: Vs[d][key]
    __shared__ unsigned short Ps[64][72];

    int t = threadIdx.x;
    int wave = t >> 6, lane = t & 63;
    int ln = lane & 15, lq = lane >> 4;
    int qt = blockIdx.x, h = blockIdx.y, b = blockIdx.z;

    const size_t bh = (size_t)b * NH + h;
    unsigned short* qp = qio + ((size_t)(b * TT + qt * 64)) * 768 + h * 64;
    const unsigned short* kp = k_ws + bh * TT * 64;
    const unsigned short* vp = v_ws + bh * TT * 64;
    const unsigned short* mp = mem_ws + (size_t)h * MEMN * 64;

    for (int i = 0; i < 2; i++) {
        int idx = i * 256 + t;
        int r = idx >> 3, c8 = (idx & 7) * 8;
        *(bf16x8_t*)&Qs[r][c8] = *(const bf16x8_t*)&qp[(size_t)r * 768 + c8];
    }

    const float CS = 0.125f * 1.44269504088896340736f;  // 1/sqrt(64) * log2(e)

    float m_i[4], l_i[4];
    f32x4_t accO[4];
    for (int r = 0; r < 4; r++) { m_i[r] = -1e30f; l_i[r] = 0.f; }
    for (int nt = 0; nt < 4; nt++) accO[nt] = (f32x4_t)(0.f);

    for (int kt = 0; kt < 16; kt++) {
        __syncthreads();
        for (int i = 0; i < 2; i++) {
            int idx = i * 256 + t;
            int r = idx >> 3, c8 = (idx & 7) * 8;
            *(bf16x8_t*)&Ks[r][c8] = *(const bf16x8_t*)&kp[((size_t)kt * 64 + r) * 64 + c8];
            bf16x8_t v = *(const bf16x8_t*)&vp[((size_t)kt * 64 + r) * 64 + c8];
            for (int j = 0; j < 8; j++) Vs[c8 + j][r] = ((unsigned short*)&v)[j];
        }
        __syncthreads();

        f32x4_t s[4];
        for (int nt = 0; nt < 4; nt++) s[nt] = (f32x4_t)(0.f);
        for (int kk = 0; kk < 2; kk++) {
            bf16x8_t a = *(bf16x8_t*)&Qs[wave * 16 + ln][kk * 32 + lq * 8];
            for (int nt = 0; nt < 4; nt++) {
                bf16x8_t bf = *(bf16x8_t*)&Ks[nt * 16 + ln][kk * 32 + lq * 8];
                s[nt] = __builtin_amdgcn_mfma_f32_16x16x32_bf16(a, bf, s[nt], 0, 0, 0);
            }
        }
        for (int nt = 0; nt < 4; nt++)
            for (int r = 0; r < 4; r++) s[nt][r] *= CS;

        float alpha[4];
        for (int r = 0; r < 4; r++) {
            float mx = fmaxf(fmaxf(s[0][r], s[1][r]), fmaxf(s[2][r], s[3][r]));
            mx = fmaxf(mx, __shfl_xor(mx, 1));
            mx = fmaxf(mx, __shfl_xor(mx, 2));
            mx = fmaxf(mx, __shfl_xor(mx, 4));
            mx = fmaxf(mx, __shfl_xor(mx, 8));
            float mnew = fmaxf(m_i[r], mx);
            alpha[r] = exp2f(m_i[r] - mnew);
            float rs = 0.f;
            for (int nt = 0; nt < 4; nt++) {
                float p = exp2f(s[nt][r] - mnew);
                s[nt][r] = p;
                rs += p;
            }
            rs += __shfl_xor(rs, 1);
            rs += __shfl_xor(rs, 2);
            rs += __shfl_xor(rs, 4);
            rs += __shfl_xor(rs, 8);
            l_i[r] = l_i[r] * alpha[r] + rs;
            m_i[r] = mnew;
        }
        for (int nt = 0; nt < 4; nt++) {
            for (int r = 0; r < 4; r++) {
                Ps[wave * 16 + lq * 4 + r][nt * 16 + ln] = f2b(s[nt][r]);
                accO[nt][r] *= alpha[r];
            }
        }
        __syncthreads();
        for (int kk = 0; kk < 2; kk++) {
            bf16x8_t a = *(bf16x8_t*)&Ps[wave * 16 + ln][kk * 32 + lq * 8];
            for (int nt = 0; nt < 4; nt++) {
                bf16x8_t bf = *(bf16x8_t*)&Vs[nt * 16 + ln][kk * 32 + lq * 8];
                accO[nt] = __builtin_amdgcn_mfma_f32_16x16x32_bf16(a, bf, accO[nt], 0, 0, 0);
            }
        }
    }

    // memory attention: independent softmax over 64 projected-memory keys
    __syncthreads();
    for (int i = 0; i < 2; i++) {
        int idx = i * 256 + t;
        int r = idx >> 3, c8 = (idx & 7) * 8;
        bf16x8_t v = *(const bf16x8_t*)&mp[r * 64 + c8];
        *(bf16x8_t*)&Ks[r][c8] = v;
        for (int j = 0; j < 8; j++) Vs[c8 + j][r] = ((unsigned short*)&v)[j];
    }
    __syncthreads();

    f32x4_t s2[4];
    for (int nt = 0; nt < 4; nt++) s2[nt] = (f32x4_t)(0.f);
    for (int kk = 0; kk < 2; kk++) {
        bf16x8_t a = *(bf16x8_t*)&Qs[wave * 16 + ln][kk * 32 + lq * 8];
        for (int nt = 0; nt < 4; nt++) {
            bf16x8_t bf = *(bf16x8_t*)&Ks[nt * 16 + ln][kk * 32 + lq * 8];
            s2[nt] = __builtin_amdgcn_mfma_f32_16x16x32_bf16(a, bf, s2[nt], 0, 0, 0);
        }
    }
    float l2[4];
    for (int r = 0; r < 4; r++) {
        for (int nt = 0; nt < 4; nt++) s2[nt][r] *= CS;
        float mx = fmaxf(fmaxf(s2[0][r], s2[1][r]), fmaxf(s2[2][r], s2[3][r]));
        mx = fmaxf(mx, __shfl_xor(mx, 1));
        mx = fmaxf(mx, __shfl_xor(mx, 2));
        mx = fmaxf(mx, __shfl_xor(mx, 4));
        mx = fmaxf(mx, __shfl_xor(mx, 8));
        float rs = 0.f;
        for (int nt = 0; nt < 4; nt++) {
            float p = exp2f(s2[nt][r] - mx);
            s2[nt][r] = p;
            rs += p;
        }
        rs += __shfl_xor(rs, 1);
        rs += __shfl_xor(rs, 2);
        rs += __shfl_xor(rs, 4);
        rs += __shfl_xor(rs, 8);
        l2[r] = rs;
    }
    for (int nt = 0; nt < 4; nt++)
        for (int r = 0; r < 4; r++)
            Ps[wave * 16 + lq * 4 + r][nt * 16 + ln] = f2b(s2[nt][r]);
    __syncthreads();

    f32x4_t accM[4];
    for (int nt = 0; nt < 4; nt++) accM[nt] = (f32x4_t)(0.f);
    for (int kk = 0; kk < 2; kk++) {
        bf16x8_t a = *(bf16x8_t*)&Ps[wave * 16 + ln][kk * 32 + lq * 8];
        for (int nt = 0; nt < 4; nt++) {
            bf16x8_t bf = *(bf16x8_t*)&Vs[nt * 16 + ln][kk * 32 + lq * 8];
            accM[nt] = __builtin_amdgcn_mfma_f32_16x16x32_bf16(a, bf, accM[nt], 0, 0, 0);
        }
    }

    // in-place write over this block's own q slice (staged to LDS above)
    for (int nt = 0; nt < 4; nt++) {
        for (int r = 0; r < 4; r++) {
            int lrow = wave * 16 + lq * 4 + r;
            int lcol = nt * 16 + ln;
            float val = accO[nt][r] / l_i[r] + accM[nt][r] / l2[r];
            qp[(size_t)lrow * 768 + lcol] = f2b(val);
        }
    }
}

// ---------------- host ----------------
extern "C" void kernel_launch(void* const* d_in, const int* in_sizes, int n_in,
                              void* d_out, int out_size, void* d_ws, size_t ws_size,
                              hipStream_t stream) {
    const float* x      = (const float*)d_in[0];
    const float* w_qkv  = (const float*)d_in[1];
    const float* b_qkv  = (const float*)d_in[2];
    const float* w_out  = (const float*)d_in[3];
    const float* b_out  = (const float*)d_in[4];
    const float* w_mem  = (const float*)d_in[5];
    const float* b_mem  = (const float*)d_in[6];
    const float* memory = (const float*)d_in[7];

    unsigned short* ws = (unsigned short*)d_ws;
    unsigned short* q_ws   = ws;                         // [B,T,C] bf16; attn writes in-place
    unsigned short* k_ws   = ws + (size_t)QSZ;           // [B,H,T,D] bf16 (v follows at +QSZ)
    unsigned short* woutT  = ws + 3 * (size_t)QSZ;       // [768][768] bf16 (N x K)
    unsigned short* mem_ws = woutT + (size_t)EMBED * EMBED;  // [H,M,D] bf16

    // x_bf16 + wqkvT park in d_out (dead before final GEMM overwrites d_out)
    unsigned short* xb    = (unsigned short*)d_out;      // [8192][768] bf16
    unsigned short* wqkvT = xb + (size_t)QSZ;            // [2304][768] bf16

    // 1) conversions
    cvt_kernel<<<QSZ / 2048, 256, 0, stream>>>(x, xb, QSZ);
    tcvt_kernel<<<dim3(QKV_N / 32, EMBED / 32), 256, 0, stream>>>(w_qkv, wqkvT, EMBED, QKV_N);
    tcvt_kernel<<<dim3(EMBED / 32, EMBED / 32), 256, 0, stream>>>(w_out, woutT, EMBED, EMBED);

    // 2) memory projection -> mem_ws [H,M,D]
    memproj_kernel<<<dim3(EMBED / 64, 1), 256, 0, stream>>>(memory, w_mem, b_mem, mem_ws);

    // 3) QKV projection: q -> q_ws [B,T,C]; k,v -> k_ws/.. [B,H,T,D]
    gemm_bt<<<dim3(QKV_N / 128, ROWS / 128), 256, 0, stream>>>(
        xb, wqkvT, b_qkv, q_ws, k_ws, nullptr, ROWS, QKV_N, EMBED, 0);

    // 4) attention (local flash + memory), in-place over q_ws
    attn_kernel<<<dim3(TT / 64, NH, BB), 256, 0, stream>>>(
        q_ws, k_ws, k_ws + (size_t)QSZ, mem_ws);

    // 5) output projection: q_ws(bf16) @ w_out + b_out -> d_out fp32
    gemm_bt<<<dim3(EMBED / 128, ROWS / 128), 256, 0, stream>>>(
        q_ws, woutT, b_out, nullptr, nullptr, (float*)d_out, ROWS, EMBED, EMBED, 1);
}

// Round 5
// 313.493 us; speedup vs baseline: 1.4897x; 1.1482x over previous
//
#include <hip/hip_runtime.h>

#define EMBED 768
#define NH 12
#define HD 64
#define MEMN 64
#define BB 8
#define TT 1024
#define ROWS 8192
#define QKV_N 2304
#define QSZ 6291456           // B*T*C = B*NH*TT*HD (elements)
#define RS 74                 // attn LDS row stride (u16): odd dword count -> no bank conflicts

typedef short bf16x8_t __attribute__((ext_vector_type(8)));
typedef float f32x4_t __attribute__((ext_vector_type(4)));

__device__ __forceinline__ unsigned short f2b(float f){
    union { float f; unsigned int i; } v; v.f = f;
    unsigned int x = v.i;
    unsigned int r = x + 0x7fffu + ((x >> 16) & 1u);
    return (unsigned short)(r >> 16);
}

// async global->LDS, 16B per lane; lds base must be wave-uniform (lane*16 implicit)
__device__ __forceinline__ void gl16(const unsigned short* g, unsigned short* l){
    __builtin_amdgcn_global_load_lds(
        (const __attribute__((address_space(1))) void*)g,
        (__attribute__((address_space(3))) void*)l,
        16, 0, 0);
}

// ---------------- flat fp32 -> bf16 convert (8 elems/thread) ----------------
__global__ __launch_bounds__(256) void cvt_kernel(
    const float* __restrict__ in, unsigned short* __restrict__ out, int n)
{
    int i = (blockIdx.x * 256 + threadIdx.x) * 8;
    if (i >= n) return;
    float4 f0 = *(const float4*)&in[i];
    float4 f1 = *(const float4*)&in[i + 4];
    union { bf16x8_t v; unsigned short s[8]; } u;
    u.s[0] = f2b(f0.x); u.s[1] = f2b(f0.y); u.s[2] = f2b(f0.z); u.s[3] = f2b(f0.w);
    u.s[4] = f2b(f1.x); u.s[5] = f2b(f1.y); u.s[6] = f2b(f1.z); u.s[7] = f2b(f1.w);
    *(bf16x8_t*)&out[i] = u.v;
}

// ------------- fp32 [R][C] -> bf16 transposed [C][R] -------------
__global__ __launch_bounds__(256) void tcvt_kernel(
    const float* __restrict__ in, unsigned short* __restrict__ out, int R, int C)
{
    __shared__ unsigned short tile[32][33];
    int bc = blockIdx.x * 32, br = blockIdx.y * 32;
    int t = threadIdx.x;
    int lr = t >> 5, lc = t & 31;
    for (int i = 0; i < 4; i++) {
        int r = lr + i * 8;
        tile[r][lc] = f2b(in[(size_t)(br + r) * C + bc + lc]);
    }
    __syncthreads();
    for (int i = 0; i < 4; i++) {
        int r = lr + i * 8;
        out[(size_t)(bc + r) * R + br + lc] = tile[lc][r];
    }
}

// ---- m97-style 128x128 bf16 GEMM: A (MxK bf16), BT (NxK bf16), bias fp32 ----
// mode 0: QKV scatter  q (pre-scaled by log2e/8) -> dq [B,T,768]; k,v -> dkv [s][B,H,T,D]
// mode 1: fp32 row-major -> df
__global__ __launch_bounds__(256) void gemm_bt(
    const unsigned short* __restrict__ A,
    const unsigned short* __restrict__ BT,
    const float* __restrict__ bias,
    unsigned short* __restrict__ dq,
    unsigned short* __restrict__ dkv,
    float* __restrict__ df,
    int M, int N, int K, int mode)
{
    __shared__ unsigned short As[4096];   // 128 x 32, no pad (global_load_lds layout)
    __shared__ unsigned short Bs[4096];
    const int t = threadIdx.x;
    const int wave = t >> 6, lane = t & 63;
    const int ln = lane & 15, lq = lane >> 4;
    const int wm = (wave >> 1) * 64, wn = (wave & 1) * 64;
    const int bm = blockIdx.y * 128, bn = blockIdx.x * 128;

    f32x4_t acc[4][4];
    for (int i = 0; i < 4; i++)
        for (int j = 0; j < 4; j++) acc[i][j] = (f32x4_t)(0.f);

    const int srow = wave * 16 + (lane >> 2);
    const int scol = (lane & 3) * 8;
    unsigned short* a0 = &As[wave * 512];
    unsigned short* a1 = &As[2048 + wave * 512];
    unsigned short* b0 = &Bs[wave * 512];
    unsigned short* b1 = &Bs[2048 + wave * 512];
    const unsigned short* Ap = A + (size_t)(bm + srow) * K + scol;
    const unsigned short* Bp = BT + (size_t)(bn + srow) * K + scol;

    for (int k0 = 0; k0 < K; k0 += 32) {
        __syncthreads();
        gl16(Ap + k0, a0);
        gl16(Ap + (size_t)64 * K + k0, a1);
        gl16(Bp + k0, b0);
        gl16(Bp + (size_t)64 * K + k0, b1);
        __syncthreads();

        bf16x8_t af[4], bfr[4];
        for (int mt = 0; mt < 4; mt++)
            af[mt] = *(bf16x8_t*)&As[(wm + mt * 16 + ln) * 32 + lq * 8];
        for (int nt = 0; nt < 4; nt++)
            bfr[nt] = *(bf16x8_t*)&Bs[(wn + nt * 16 + ln) * 32 + lq * 8];
        for (int mt = 0; mt < 4; mt++)
            for (int nt = 0; nt < 4; nt++)
                acc[mt][nt] = __builtin_amdgcn_mfma_f32_16x16x32_bf16(
                    af[mt], bfr[nt], acc[mt][nt], 0, 0, 0);
    }

    const float QSCALE = 0.125f * 1.44269504088896340736f;  // folded softmax scale (exp2 domain)
    for (int nt = 0; nt < 4; nt++) {
        int c = bn + wn + nt * 16 + ln;
        float bv = bias[c];
        for (int mt = 0; mt < 4; mt++) {
            for (int r = 0; r < 4; r++) {
                int row = bm + wm + mt * 16 + lq * 4 + r;
                float val = acc[mt][nt][r] + bv;
                if (mode == 0) {
                    int bb = row >> 10, tt = row & 1023;
                    int s = c / 768; int rem = c - s * 768;
                    if (s == 0) {
                        dq[(size_t)row * 768 + rem] = f2b(val * QSCALE);
                    } else {
                        int h = rem >> 6, d = rem & 63;
                        dkv[(size_t)(s - 1) * QSZ +
                            (((size_t)(bb * 12 + h) * 1024 + tt) << 6) + d] = f2b(val);
                    }
                } else {
                    df[(size_t)row * N + c] = val;
                }
            }
        }
    }
}

// ---- memory projection (tiny): fp32 A (64x768), fp32 B (768x768) -> bf16 [H,M,D] ----
__global__ __launch_bounds__(256) void memproj_kernel(
    const float* __restrict__ A,
    const float* __restrict__ B,
    const float* __restrict__ bias,
    unsigned short* __restrict__ dmem)
{
    __shared__ unsigned short As[64][40];
    __shared__ unsigned short Bs[64][40];   // transposed: Bs[n][k]
    int t = threadIdx.x;
    int wave = t >> 6, lane = t & 63;
    int ln = lane & 15, lq = lane >> 4;
    int bn = blockIdx.x * 64;
    const int K = EMBED, N = EMBED;

    f32x4_t acc[4];
    for (int i = 0; i < 4; i++) acc[i] = (f32x4_t)(0.f);

    int sm = t >> 2, sk = (t & 3) * 8;
    int bk = t >> 3, bn8 = (t & 7) * 8;

    for (int k0 = 0; k0 < K; k0 += 32) {
        __syncthreads();
        {
            float4 f0 = *(const float4*)&A[(size_t)sm * K + k0 + sk];
            float4 f1 = *(const float4*)&A[(size_t)sm * K + k0 + sk + 4];
            unsigned short* ap = &As[sm][sk];
            ap[0] = f2b(f0.x); ap[1] = f2b(f0.y); ap[2] = f2b(f0.z); ap[3] = f2b(f0.w);
            ap[4] = f2b(f1.x); ap[5] = f2b(f1.y); ap[6] = f2b(f1.z); ap[7] = f2b(f1.w);
        }
        {
            float4 g0 = *(const float4*)&B[(size_t)(k0 + bk) * N + bn + bn8];
            float4 g1 = *(const float4*)&B[(size_t)(k0 + bk) * N + bn + bn8 + 4];
            Bs[bn8 + 0][bk] = f2b(g0.x); Bs[bn8 + 1][bk] = f2b(g0.y);
            Bs[bn8 + 2][bk] = f2b(g0.z); Bs[bn8 + 3][bk] = f2b(g0.w);
            Bs[bn8 + 4][bk] = f2b(g1.x); Bs[bn8 + 5][bk] = f2b(g1.y);
            Bs[bn8 + 6][bk] = f2b(g1.z); Bs[bn8 + 7][bk] = f2b(g1.w);
        }
        __syncthreads();
        bf16x8_t a = *(bf16x8_t*)&As[wave * 16 + ln][lq * 8];
        for (int nt = 0; nt < 4; nt++) {
            bf16x8_t bf = *(bf16x8_t*)&Bs[nt * 16 + ln][lq * 8];
            acc[nt] = __builtin_amdgcn_mfma_f32_16x16x32_bf16(a, bf, acc[nt], 0, 0, 0);
        }
    }

    for (int nt = 0; nt < 4; nt++) {
        int c = bn + nt * 16 + ln;
        float bv = bias[c];
        for (int r = 0; r < 4; r++) {
            int row = wave * 16 + lq * 4 + r;   // 0..63
            int h = c >> 6, d = c & 63;
            dmem[((h * 64 + row) << 6) + d] = f2b(acc[nt][r] + bv);
        }
    }
}

// ---- flash attention, unnormalized exp2 (scores bounded; scale pre-folded into q) ----
// + memory attention; in-place over q. XCD-swizzled flat grid (1536 blocks).
__global__ __launch_bounds__(256) void attn_kernel(
    unsigned short* __restrict__ qio,           // [B,T,768] bf16, in/out (q pre-scaled)
    const unsigned short* __restrict__ k_ws,    // [B,H,T,D] bf16
    const unsigned short* __restrict__ v_ws,    // [B,H,T,D] bf16
    const unsigned short* __restrict__ mem_ws)  // [H,M,D]   bf16
{
    __shared__ unsigned short Qs[64 * RS];
    __shared__ unsigned short Ks[64 * RS];
    __shared__ unsigned short Vs[64 * RS];   // transposed: Vs[d][key]
    __shared__ unsigned short Ps[64 * RS];

    const int t = threadIdx.x;
    const int wave = t >> 6, lane = t & 63;
    const int ln = lane & 15, lq = lane >> 4;

    // XCD swizzle: all 16 q-tiles of one (b,h) land on one XCD -> K/V stays in its L2
    int bid = blockIdx.x;
    int xcd = bid & 7, rest = bid >> 3;
    int bh = xcd * 12 + (rest >> 4);   // 0..95 == b*NH + h
    int qt = rest & 15;
    int b = bh / 12, h = bh - b * 12;

    unsigned short* qp = qio + ((size_t)(b * TT + qt * 64)) * 768 + h * 64;
    const unsigned short* kp = k_ws + (size_t)bh * TT * 64;
    const unsigned short* vp = v_ws + (size_t)bh * TT * 64;
    const unsigned short* mp = mem_ws + (size_t)h * MEMN * 64;

    for (int i = 0; i < 2; i++) {
        int idx = i * 256 + t;
        int r = idx >> 3, c8 = (idx & 7) * 8;
        *(bf16x8_t*)&Qs[r * RS + c8] = *(const bf16x8_t*)&qp[(size_t)r * 768 + c8];
    }

    float lsum[4] = {0.f, 0.f, 0.f, 0.f};
    f32x4_t accO[4];
    for (int nt = 0; nt < 4; nt++) accO[nt] = (f32x4_t)(0.f);

    for (int kt = 0; kt < 16; kt++) {
        __syncthreads();
        for (int i = 0; i < 2; i++) {
            int idx = i * 256 + t;
            int r = idx >> 3, c8 = (idx & 7) * 8;
            *(bf16x8_t*)&Ks[r * RS + c8] = *(const bf16x8_t*)&kp[((size_t)kt * 64 + r) * 64 + c8];
            union { bf16x8_t v; unsigned short s[8]; } u;
            u.v = *(const bf16x8_t*)&vp[((size_t)kt * 64 + r) * 64 + c8];
            for (int j = 0; j < 8; j++) Vs[(c8 + j) * RS + r] = u.s[j];
        }
        __syncthreads();

        f32x4_t s[4];
        for (int nt = 0; nt < 4; nt++) s[nt] = (f32x4_t)(0.f);
        for (int kk = 0; kk < 2; kk++) {
            bf16x8_t a = *(bf16x8_t*)&Qs[(wave * 16 + ln) * RS + kk * 32 + lq * 8];
            for (int nt = 0; nt < 4; nt++) {
                bf16x8_t bf = *(bf16x8_t*)&Ks[(nt * 16 + ln) * RS + kk * 32 + lq * 8];
                s[nt] = __builtin_amdgcn_mfma_f32_16x16x32_bf16(a, bf, s[nt], 0, 0, 0);
            }
        }
        // unnormalized: p = exp2(score*log2e/8); scale already folded into q
        for (int nt = 0; nt < 4; nt++) {
            for (int r = 0; r < 4; r++) {
                float p = exp2f(s[nt][r]);
                lsum[r] += p;
                Ps[(wave * 16 + lq * 4 + r) * RS + nt * 16 + ln] = f2b(p);
            }
        }
        // Ps slab is wave-private (write rows == read rows): no barrier needed
        for (int kk = 0; kk < 2; kk++) {
            bf16x8_t a = *(bf16x8_t*)&Ps[(wave * 16 + ln) * RS + kk * 32 + lq * 8];
            for (int nt = 0; nt < 4; nt++) {
                bf16x8_t bf = *(bf16x8_t*)&Vs[(nt * 16 + ln) * RS + kk * 32 + lq * 8];
                accO[nt] = __builtin_amdgcn_mfma_f32_16x16x32_bf16(a, bf, accO[nt], 0, 0, 0);
            }
        }
    }

    // memory attention: independent unnormalized softmax over 64 projected-memory keys
    __syncthreads();
    for (int i = 0; i < 2; i++) {
        int idx = i * 256 + t;
        int r = idx >> 3, c8 = (idx & 7) * 8;
        union { bf16x8_t v; unsigned short s[8]; } u;
        u.v = *(const bf16x8_t*)&mp[r * 64 + c8];
        *(bf16x8_t*)&Ks[r * RS + c8] = u.v;
        for (int j = 0; j < 8; j++) Vs[(c8 + j) * RS + r] = u.s[j];
    }
    __syncthreads();

    f32x4_t s2[4];
    for (int nt = 0; nt < 4; nt++) s2[nt] = (f32x4_t)(0.f);
    for (int kk = 0; kk < 2; kk++) {
        bf16x8_t a = *(bf16x8_t*)&Qs[(wave * 16 + ln) * RS + kk * 32 + lq * 8];
        for (int nt = 0; nt < 4; nt++) {
            bf16x8_t bf = *(bf16x8_t*)&Ks[(nt * 16 + ln) * RS + kk * 32 + lq * 8];
            s2[nt] = __builtin_amdgcn_mfma_f32_16x16x32_bf16(a, bf, s2[nt], 0, 0, 0);
        }
    }
    float l2[4] = {0.f, 0.f, 0.f, 0.f};
    for (int nt = 0; nt < 4; nt++) {
        for (int r = 0; r < 4; r++) {
            float p = exp2f(s2[nt][r]);
            l2[r] += p;
            Ps[(wave * 16 + lq * 4 + r) * RS + nt * 16 + ln] = f2b(p);
        }
    }
    f32x4_t accM[4];
    for (int nt = 0; nt < 4; nt++) accM[nt] = (f32x4_t)(0.f);
    for (int kk = 0; kk < 2; kk++) {
        bf16x8_t a = *(bf16x8_t*)&Ps[(wave * 16 + ln) * RS + kk * 32 + lq * 8];
        for (int nt = 0; nt < 4; nt++) {
            bf16x8_t bf = *(bf16x8_t*)&Vs[(nt * 16 + ln) * RS + kk * 32 + lq * 8];
            accM[nt] = __builtin_amdgcn_mfma_f32_16x16x32_bf16(a, bf, accM[nt], 0, 0, 0);
        }
    }

    // single deferred cross-lane reduction of the denominators (ln dimension = key lanes)
    float inv[4], inv2[4];
    for (int r = 0; r < 4; r++) {
        float a = lsum[r], c = l2[r];
        a += __shfl_xor(a, 1); a += __shfl_xor(a, 2);
        a += __shfl_xor(a, 4); a += __shfl_xor(a, 8);
        c += __shfl_xor(c, 1); c += __shfl_xor(c, 2);
        c += __shfl_xor(c, 4); c += __shfl_xor(c, 8);
        inv[r] = 1.f / a;
        inv2[r] = 1.f / c;
    }

    // in-place write over this block's own q slice (staged to LDS at entry)
    for (int nt = 0; nt < 4; nt++) {
        for (int r = 0; r < 4; r++) {
            int lrow = wave * 16 + lq * 4 + r;
            int lcol = nt * 16 + ln;
            float val = accO[nt][r] * inv[r] + accM[nt][r] * inv2[r];
            qp[(size_t)lrow * 768 + lcol] = f2b(val);
        }
    }
}

// ---------------- host ----------------
extern "C" void kernel_launch(void* const* d_in, const int* in_sizes, int n_in,
                              void* d_out, int out_size, void* d_ws, size_t ws_size,
                              hipStream_t stream) {
    const float* x      = (const float*)d_in[0];
    const float* w_qkv  = (const float*)d_in[1];
    const float* b_qkv  = (const float*)d_in[2];
    const float* w_out  = (const float*)d_in[3];
    const float* b_out  = (const float*)d_in[4];
    const float* w_mem  = (const float*)d_in[5];
    const float* b_mem  = (const float*)d_in[6];
    const float* memory = (const float*)d_in[7];

    unsigned short* ws = (unsigned short*)d_ws;
    unsigned short* q_ws   = ws;                         // [B,T,C] bf16; attn writes in-place
    unsigned short* k_ws   = ws + (size_t)QSZ;           // [B,H,T,D] bf16 (v follows at +QSZ)
    unsigned short* woutT  = ws + 3 * (size_t)QSZ;       // [768][768] bf16 (N x K)
    unsigned short* mem_ws = woutT + (size_t)EMBED * EMBED;  // [H,M,D] bf16

    // x_bf16 + wqkvT park in d_out (dead before final GEMM overwrites d_out)
    unsigned short* xb    = (unsigned short*)d_out;      // [8192][768] bf16
    unsigned short* wqkvT = xb + (size_t)QSZ;            // [2304][768] bf16

    // 1) conversions
    cvt_kernel<<<QSZ / 2048, 256, 0, stream>>>(x, xb, QSZ);
    tcvt_kernel<<<dim3(QKV_N / 32, EMBED / 32), 256, 0, stream>>>(w_qkv, wqkvT, EMBED, QKV_N);
    tcvt_kernel<<<dim3(EMBED / 32, EMBED / 32), 256, 0, stream>>>(w_out, woutT, EMBED, EMBED);

    // 2) memory projection -> mem_ws [H,M,D]
    memproj_kernel<<<dim3(EMBED / 64, 1), 256, 0, stream>>>(memory, w_mem, b_mem, mem_ws);

    // 3) QKV projection: q (pre-scaled) -> q_ws [B,T,C]; k,v -> k_ws/.. [B,H,T,D]
    gemm_bt<<<dim3(QKV_N / 128, ROWS / 128), 256, 0, stream>>>(
        xb, wqkvT, b_qkv, q_ws, k_ws, nullptr, ROWS, QKV_N, EMBED, 0);

    // 4) attention (local flash + memory), in-place over q_ws; XCD-swizzled flat grid
    attn_kernel<<<16 * NH * BB, 256, 0, stream>>>(
        q_ws, k_ws, k_ws + (size_t)QSZ, mem_ws);

    // 5) output projection: q_ws(bf16) @ w_out + b_out -> d_out fp32
    gemm_bt<<<dim3(EMBED / 128, ROWS / 128), 256, 0, stream>>>(
        q_ws, woutT, b_out, nullptr, nullptr, (float*)d_out, ROWS, EMBED, EMBED, 1);
}